// Round 1
// 134.281 us; speedup vs baseline: 1.0113x; 1.0113x over previous
//
#include <hip/hip_runtime.h>
#include <stdint.h>

typedef unsigned short u16;
typedef unsigned int u32;
typedef __attribute__((ext_vector_type(4))) float floatx4;
typedef __attribute__((ext_vector_type(8))) short short8;

// Dtypes fixed: float32 tensors (R3 proof), int32 edge_index (R5 page-fault
// on int64 + R3/R4 passing on int32 path).
// R9: grid.sync ~100us/barrier -> multi-kernel pipeline. ~85us of the timed
// window is fixed harness restore/poison traffic; controllable ~52us.
// R11 WIN: fixed-capacity bucketing, 4 dispatches (158.9 -> 137.4us).
// R12: GEMM (Mt,8)->(Mt,4), shared As + double Bs: A-traffic halved.
// R13: GEMM staging via global_load_lds (dwordx4) + involutive XOR swizzle
//      (pre-swizzled global source, linear LDS dest, swizzled ds_read).
//      Removes the reg->LDS round-trip (m151: ~35% staging tax).

#define CAP 128   // bucket capacity per node; deg ~ Poisson(16), P(>128) ~ 0

static __device__ __forceinline__ float bfhi2f(u32 hi) {
    union { u32 i; float f; } v; v.i = hi; return v.f;
}
static __device__ __forceinline__ u16 f2bf(float f) {
    union { float f; u32 i; } v; v.f = f;
    u32 r = v.i + 0x7fffu + ((v.i >> 16) & 1u);
    return (u16)(r >> 16);
}
static __device__ __forceinline__ uint4 pack8(const float* s) {
    float4 a = *(const float4*)s, b = *(const float4*)(s + 4);
    uint4 p;
    p.x = (u32)f2bf(a.x) | ((u32)f2bf(a.y) << 16);
    p.y = (u32)f2bf(a.z) | ((u32)f2bf(a.w) << 16);
    p.z = (u32)f2bf(b.x) | ((u32)f2bf(b.y) << 16);
    p.w = (u32)f2bf(b.z) | ((u32)f2bf(b.w) << 16);
    return p;
}
static __device__ __forceinline__ void acc8(float* acc, uint4 d) {
    acc[0] += bfhi2f(d.x << 16); acc[1] += bfhi2f(d.x & 0xffff0000u);
    acc[2] += bfhi2f(d.y << 16); acc[3] += bfhi2f(d.y & 0xffff0000u);
    acc[4] += bfhi2f(d.z << 16); acc[5] += bfhi2f(d.z & 0xffff0000u);
    acc[6] += bfhi2f(d.w << 16); acc[7] += bfhi2f(d.w & 0xffff0000u);
}

// async 16B global -> LDS (linear dest: wave-uniform base + lane*16)
static __device__ __forceinline__ void gload_lds16(const u16* g, u16* l) {
    __builtin_amdgcn_global_load_lds(
        (const __attribute__((address_space(1))) void*)g,
        (__attribute__((address_space(3))) void*)l, 16, 0, 0);
}

// ---------------- fused prep: x->bf16, W->bf16 (concat), bucket-fill ----------------
// Wb layout: [Wsrel(s2) | Wsroot(s2) | Wvrel(s5) | Wvroot(s5)]

__global__ __launch_bounds__(256) void prep_kernel(
        const float* __restrict__ x, u16* __restrict__ xb, int n8,
        const float* __restrict__ w2, const float* __restrict__ w3,
        const float* __restrict__ w5, const float* __restrict__ w6,
        u16* __restrict__ Wb, int s2, int s5, int nw8,
        const int* __restrict__ ei, int E, int N,
        int* __restrict__ cursor, int* __restrict__ edge_dst,
        int nb_x, int nb_w) {
    const int b = blockIdx.x, tid = threadIdx.x;
    if (b < nb_x) {
        int t = b * 256 + tid;
        if (t < n8) *(uint4*)(xb + (size_t)t * 8) = pack8(x + (size_t)t * 8);
    } else if (b < nb_x + nb_w) {
        int t = (b - nb_x) * 256 + tid;
        if (t < nw8) {
            int g = t * 8;
            const float* src; int loc;
            if (g < s2)               { src = w2; loc = g; }
            else if (g < 2 * s2)      { src = w3; loc = g - s2; }
            else if (g < 2 * s2 + s5) { src = w5; loc = g - 2 * s2; }
            else                      { src = w6; loc = g - 2 * s2 - s5; }
            *(uint4*)(Wb + g) = pack8(src + loc);
        }
    } else {
        int e = (b - nb_x - nb_w) * 256 + tid;
        if (e < E) {
            unsigned r = (unsigned)ei[e];
            unsigned c = (unsigned)ei[E + e];
            if (r < (unsigned)N && c < (unsigned)N) {
                int slot = atomicAdd(&cursor[r], 1);
                if (slot < CAP) edge_dst[(size_t)r * CAP + slot] = (int)c;
            }
        }
    }
}

// ---------------- aggregate: agg[n,0:512] (bf16) = sum over in-edges ----------------
// One wave per node; 16-deep prefetch via coalesced bucket load + shfl bcast.

__global__ __launch_bounds__(256) void gather_kernel(
        const u16* __restrict__ xb, const int* __restrict__ cursor,
        const int* __restrict__ edge_dst, u16* __restrict__ agg, int N) {
    int gw   = (blockIdx.x * 256 + threadIdx.x) >> 6;
    int lane = threadIdx.x & 63;
    if (gw >= N) return;
    int deg = cursor[gw];
    if (deg > CAP) deg = CAP;
    const int beg = gw * CAP, end = beg + deg;
    float acc[8] = {0.f,0.f,0.f,0.f,0.f,0.f,0.f,0.f};
    const u16* xl = xb + (size_t)lane * 8;
    int e = beg;
    for (; e + 16 <= end; e += 16) {
        int myid = edge_dst[e + (lane & 15)];
        uint4 d[16];
#pragma unroll
        for (int u = 0; u < 16; ++u) {
            int c = __shfl(myid, u);
            d[u] = *(const uint4*)(xl + (size_t)c * 512);
        }
#pragma unroll
        for (int u = 0; u < 16; ++u) acc8(acc, d[u]);
    }
    if (e + 8 <= end) {
        int myid = edge_dst[e + (lane & 7)];
        uint4 d[8];
#pragma unroll
        for (int u = 0; u < 8; ++u) {
            int c = __shfl(myid, u);
            d[u] = *(const uint4*)(xl + (size_t)c * 512);
        }
#pragma unroll
        for (int u = 0; u < 8; ++u) acc8(acc, d[u]);
        e += 8;
    }
    if (e + 4 <= end) {
        int myid = edge_dst[e + (lane & 3)];
        uint4 d[4];
#pragma unroll
        for (int u = 0; u < 4; ++u) {
            int c = __shfl(myid, u);
            d[u] = *(const uint4*)(xl + (size_t)c * 512);
        }
#pragma unroll
        for (int u = 0; u < 4; ++u) acc8(acc, d[u]);
        e += 4;
    }
    for (; e < end; ++e) {
        int c = edge_dst[e];
        acc8(acc, *(const uint4*)(xl + (size_t)c * 512));
    }
    uint4 p;
    p.x = (u32)f2bf(acc[0]) | ((u32)f2bf(acc[1]) << 16);
    p.y = (u32)f2bf(acc[2]) | ((u32)f2bf(acc[3]) << 16);
    p.z = (u32)f2bf(acc[4]) | ((u32)f2bf(acc[5]) << 16);
    p.w = (u32)f2bf(acc[6]) | ((u32)f2bf(acc[7]) << 16);
    *(uint4*)(agg + (size_t)gw * 512 + (size_t)lane * 8) = p;
}

// ---------------- fused output GEMM (64 rows x 128 cols per block, BK=128) ----------------
// grid (Mt, 4):
//   unit 0:    out[:, 0:128]                 = x_s@Ws_root^T + agg_s@Ws_rel^T + b
//   unit 1..3: out[:, 128+(u-1)*128 ..+127]  = x_v@Wv_root^T + agg_v@Wv_rel^T
// Staging: global_load_lds dwordx4, 1 KB window per wave-instruction (4 rows x 256B).
// Swizzle (rule #21 both-sides): logical 16B-chunk p of row r lives at phys chunk
// p^(r&7); loader pre-swizzles the GLOBAL source chunk, ds_read applies same XOR.
// Bank check: phys&7 = (p&7)^(r&7) covers all 8 bank-groups per 8-row stripe -> 2-way max (free).

__global__ __launch_bounds__(256, 3) void gemm_kernel(
        const u16* __restrict__ xb, const u16* __restrict__ agg,
        const u16* __restrict__ Wb, const float* __restrict__ bias,
        int s2, int s5, float* __restrict__ out, int N) {
    const int unit = blockIdx.y;
    const bool is_scalar = (unit == 0);

    const int Kw      = is_scalar ? 128 : 384;
    const int K       = 2 * Kw;
    const int selfOff = is_scalar ? 0 : 128;
    const int j0      = is_scalar ? 0 : (unit - 1) * 128;
    const int outOff  = is_scalar ? 0 : 128;
    const u16* Wrel   = is_scalar ? Wb : (Wb + 2 * s2);
    const u16* Wroot  = is_scalar ? (Wb + s2) : (Wb + 2 * s2 + s5);

    __shared__ u16 As[64 * 128];
    __shared__ u16 Bs[2][64 * 128];

    const int row0 = blockIdx.x * 64;
    const int tid  = threadIdx.x;
    const int lane = tid & 63, wid = tid >> 6;
    const int mBase = (wid >> 1) * 32, nBase = (wid & 1) * 32;
    const int lrow = lane & 15;
    const int lchv = lane >> 4;      // 0..3: fragment chunk sub-index
    const int lhi  = lane >> 4;      // 0..3: row within 4-row staging window
    const int lp   = lane & 15;      // 16B slot within staging window row group

    floatx4 acc[2][2][2];   // [jt][i][j]
#pragma unroll
    for (int jt = 0; jt < 2; ++jt)
#pragma unroll
        for (int i = 0; i < 2; ++i)
#pragma unroll
            for (int j = 0; j < 2; ++j) acc[jt][i][j] = (floatx4){0.f, 0.f, 0.f, 0.f};

    for (int k0 = 0; k0 < K; k0 += 128) {
        const bool selfPhase = (k0 < Kw);
        const int ks   = selfPhase ? k0 : (k0 - Kw);
        const int acol = selfOff + ks;
        const u16* Asrc = selfPhase ? xb : agg;
        const u16* Wsrc = selfPhase ? Wroot : Wrel;
        if (k0 > 0) __syncthreads();
        // stage A: 64 rows x 128 cols; 16 windows of 1KB (4 rows each), 4 per wave
#pragma unroll
        for (int it = 0; it < 4; ++it) {
            int win = wid * 4 + it;              // 0..15
            int r   = win * 4 + lhi;             // row in tile 0..63
            int ar  = row0 + r; if (ar >= N) ar = N - 1;
            int sc  = lp ^ (r & 7);              // pre-swizzled source chunk
            gload_lds16(Asrc + (size_t)ar * 512 + acol + (sc << 3),
                        As + win * 512);
        }
        // stage B: two 64x128 j-tiles; 32 windows, 8 per wave
#pragma unroll
        for (int it = 0; it < 8; ++it) {
            int win = wid * 8 + it;              // 0..31
            int jt  = win >> 4;
            int wl  = win & 15;                  // window within tile
            int r   = wl * 4 + lhi;              // row in tile 0..63
            int sc  = lp ^ (r & 7);
            gload_lds16(Wsrc + (size_t)(j0 + jt * 64 + r) * Kw + ks + (sc << 3),
                        Bs[jt] + wl * 512);
        }
        __syncthreads();
#pragma unroll
        for (int kk = 0; kk < 128; kk += 32) {
            const int pA = (kk >> 3) + lchv;     // logical chunk 0..15
            short8 a[2], b[2][2];
#pragma unroll
            for (int i = 0; i < 2; ++i) {
                int row = mBase + i * 16 + lrow;
                a[i] = *(const short8*)&As[row * 128 + ((pA ^ (row & 7)) << 3)];
            }
#pragma unroll
            for (int jt = 0; jt < 2; ++jt)
#pragma unroll
                for (int j = 0; j < 2; ++j) {
                    int row = nBase + j * 16 + lrow;
                    b[jt][j] = *(const short8*)&Bs[jt][row * 128 + ((pA ^ (row & 7)) << 3)];
                }
#pragma unroll
            for (int jt = 0; jt < 2; ++jt)
#pragma unroll
                for (int i = 0; i < 2; ++i)
#pragma unroll
                    for (int j = 0; j < 2; ++j)
                        acc[jt][i][j] = __builtin_amdgcn_mfma_f32_16x16x32_bf16(
                            a[i], b[jt][j], acc[jt][i][j], 0, 0, 0);
        }
    }

    // epilogue: C/D layout col=lane&15, row=(lane>>4)*4+reg
    const int lcol = lane & 15;
    const int lrow4 = (lane >> 4) * 4;
#pragma unroll
    for (int jt = 0; jt < 2; ++jt) {
#pragma unroll
        for (int i = 0; i < 2; ++i) {
#pragma unroll
            for (int j = 0; j < 2; ++j) {
                int col = jt * 64 + nBase + j * 16 + lcol;   // 0..127 within block span
                float bv = is_scalar ? bias[j0 + col] : 0.f;
#pragma unroll
                for (int r = 0; r < 4; ++r) {
                    int row = row0 + mBase + i * 16 + lrow4 + r;
                    if (row < N)
                        out[(size_t)row * 512 + outOff + j0 + col] = acc[jt][i][j][r] + bv;
                }
            }
        }
    }
}

extern "C" void kernel_launch(void* const* d_in, const int* in_sizes, int n_in,
                              void* d_out, int out_size, void* d_ws, size_t ws_size,
                              hipStream_t stream) {
    const float* x      = (const float*)d_in[0];
    const int*   ei     = (const int*)d_in[1];
    const float* Wsrel  = (const float*)d_in[2];
    const float* Wsroot = (const float*)d_in[3];
    const float* bs     = (const float*)d_in[4];
    const float* Wvrel  = (const float*)d_in[5];
    const float* Wvroot = (const float*)d_in[6];
    float* out = (float*)d_out;

    const int N  = in_sizes[0] / 512;
    const int E  = in_sizes[1] / 2;
    const int s2 = in_sizes[2];          // HIDDEN^2
    const int s5 = in_sizes[5];          // (3*HIDDEN)^2
    const int Nx = in_sizes[0];          // N*512
    const int Mt = (N + 63) / 64;

    // ws layout (~27 MB)
    char* ws = (char*)d_ws;
    size_t off = 0;
    int* cursor = (int*)(ws + off);   off += (size_t)N * 4;            off = (off + 255) & ~(size_t)255;
    int* edge_dst = (int*)(ws + off); off += (size_t)N * CAP * 4;      off = (off + 255) & ~(size_t)255;
    u16* Wb = (u16*)(ws + off);       off += (size_t)(2*s2 + 2*s5) * 2; off = (off + 255) & ~(size_t)255;
    u16* agg = (u16*)(ws + off);      off += (size_t)Nx * 2;           off = (off + 255) & ~(size_t)255;
    u16* x_bf = (u16*)(ws + off);

    const int n8   = Nx / 8;
    const int nw8  = (2 * s2 + 2 * s5) / 8;
    const int nb_x = (n8 + 255) / 256;
    const int nb_w = (nw8 + 255) / 256;
    const int nb_c = (E + 255) / 256;

    hipMemsetAsync(cursor, 0, (size_t)N * 4, stream);
    prep_kernel<<<nb_x + nb_w + nb_c, 256, 0, stream>>>(
        x, x_bf, n8, Wsrel, Wsroot, Wvrel, Wvroot, Wb, s2, s5, nw8,
        ei, E, N, cursor, edge_dst, nb_x, nb_w);
    gather_kernel<<<(N * 64 + 255) / 256, 256, 0, stream>>>(
        x_bf, cursor, edge_dst, agg, N);
    dim3 grid(Mt, 4);
    gemm_kernel<<<grid, 256, 0, stream>>>(x_bf, agg, Wb, bs, s2, s5, out, N);
}